// Round 3
// baseline (1839.472 us; speedup 1.0000x reference)
//
#include <hip/hip_runtime.h>

#define B_ 128
#define S_ 1024
#define H_ 256
#define V_ 256

// LDS layout: 16-float chunks at 20-word stride (spreads the 16 per-wave
// ds_read_b128 addresses across all 32 banks at 2-way aliasing = free).
#define CH_W 20
#define LIDX(e) ((((e) >> 4) * CH_W) + ((e) & 15))
#define HBUF_W (16 * CH_W)  // 320 words per h-vector

// DPP rotate-reduce within each 16-lane row: all 16 lanes end with the sum.
#define DPP_ADD(v, ctrl)                                                      \
  v += __int_as_float(                                                        \
      __builtin_amdgcn_update_dpp(0, __float_as_int(v), ctrl, 0xF, 0xF, true))

__device__ __forceinline__ float reduce16(float v) {
  DPP_ADD(v, 0x128);  // row_ror:8
  DPP_ADD(v, 0x124);  // row_ror:4
  DPP_ADD(v, 0x122);  // row_ror:2
  DPP_ADD(v, 0x121);  // row_ror:1
  return v;
}

// 3-level cndmask tree: pick d[j] (j = lane's qq&7) without dynamic indexing.
__device__ __forceinline__ float select8(const float* d, int j) {
  float s01 = (j & 1) ? d[1] : d[0];
  float s23 = (j & 1) ? d[3] : d[2];
  float s45 = (j & 1) ? d[5] : d[4];
  float s67 = (j & 1) ? d[7] : d[6];
  float a = (j & 2) ? s23 : s01;
  float b = (j & 2) ? s67 : s45;
  return (j & 4) ? b : a;
}

__device__ __forceinline__ float tanh_fast(float x) {
  x = fminf(fmaxf(x, -15.f), 15.f);
  float e = __expf(2.f * x);
  return (e - 1.f) * __builtin_amdgcn_rcpf(e + 1.f);
}

// 8x16 dot block: p[j] = w[j][:]·h_chunk (16 floats at this thread's qq)
#define DOT8x16(p, w, hq4)                                                    \
  {                                                                           \
    float4 h0 = hq4[0], h1 = hq4[1], h2 = hq4[2], h3 = hq4[3];                \
    _Pragma("unroll") for (int j = 0; j < 8; ++j) {                           \
      float s = 0.f;                                                          \
      s += w[j][0].x * h0.x; s += w[j][0].y * h0.y;                           \
      s += w[j][0].z * h0.z; s += w[j][0].w * h0.w;                           \
      s += w[j][1].x * h1.x; s += w[j][1].y * h1.y;                           \
      s += w[j][1].z * h1.z; s += w[j][1].w * h1.w;                           \
      s += w[j][2].x * h2.x; s += w[j][2].y * h2.y;                           \
      s += w[j][2].z * h2.z; s += w[j][2].w * h2.w;                           \
      s += w[j][3].x * h3.x; s += w[j][3].y * h3.y;                           \
      s += w[j][3].z * h3.z; s += w[j][3].w * h3.w;                           \
      p[j] = s;                                                               \
    }                                                                         \
  }

#define LOAD_W8(w, SRC, row_of_j, kq)                                         \
  _Pragma("unroll") for (int j = 0; j < 8; ++j) {                             \
    const float4* W =                                                         \
        reinterpret_cast<const float4*>((SRC) + (size_t)(row_of_j)*H_ + (kq) * 16); \
    w[j][0] = W[0]; w[j][1] = W[1]; w[j][2] = W[2]; w[j][3] = W[3];           \
  }

// ---------------------------------------------------------------------------
// K1: A[v,h] = embed[v,:]·Wxh[h,:] + bxh[h] + bhh[h]   (unchanged, tiny)
// ---------------------------------------------------------------------------
__global__ __launch_bounds__(512, 2) void prep_A(const float* __restrict__ embed,
                                                 const float* __restrict__ Wxh,
                                                 const float* __restrict__ bxh,
                                                 const float* __restrict__ bhh,
                                                 float* __restrict__ A) {
  const int v = blockIdx.x, t = threadIdx.x;
  const int qq = t & 15, og = t >> 4;

  __shared__ __align__(16) float erow[HBUF_W];
  if (t < 64)
    reinterpret_cast<float4*>(&erow[(t >> 2) * CH_W])[t & 3] =
        reinterpret_cast<const float4*>(embed + v * H_)[t];

  float4 w[8][4];
  LOAD_W8(w, Wxh, og + 32 * j, qq);
  __syncthreads();

  const float4* hq4 = reinterpret_cast<const float4*>(&erow[qq * CH_W]);
  float p[8];
  DOT8x16(p, w, hq4);
  float d[8];
#pragma unroll
  for (int j = 0; j < 8; ++j) d[j] = reduce16(p[j]);
  const int jsel = qq & 7;
  const int o_sel = og + 32 * jsel;
  float r = select8(d, jsel);
  if (qq < 8) A[v * H_ + o_sel] = r + bxh[o_sel] + bhh[o_sel];
}

// ---------------------------------------------------------------------------
// K2: Elman recurrence. One block/batch; thread (og,qq) owns outputs
// {og+32j} with k-chunk qq*16. 4 ds_read_b128/thread/step; DPP reduce;
// distributed tanh via cndmask-select; one barrier per step.
// ---------------------------------------------------------------------------
__global__ __launch_bounds__(512, 2) void rnn_fwd(const int* __restrict__ x,
                                                  const float* __restrict__ A,
                                                  const float* __restrict__ Whh,
                                                  float* __restrict__ hs) {
  const int t = threadIdx.x, b = blockIdx.x;
  const int qq = t & 15, og = t >> 4;
  const int jsel = qq & 7;
  const int o_sel = og + 32 * jsel;

  float4 w[8][4];
  LOAD_W8(w, Whh, og + 32 * j, qq);

  __shared__ __align__(16) float hbuf[2][HBUF_W];
  if (t < H_) hbuf[0][LIDX(t)] = 0.f;
  const int* xb = x + b * S_;
  float* hsb = hs + (size_t)b * S_ * H_;
  float a = A[xb[0] * H_ + o_sel];
  __syncthreads();

  for (int s = 0; s < S_; ++s) {
    const float4* hq4 =
        reinterpret_cast<const float4*>(&hbuf[s & 1][qq * CH_W]);
    float a_next = 0.f;
    if (s + 1 < S_) a_next = A[xb[s + 1] * H_ + o_sel];

    float p[8];
    DOT8x16(p, w, hq4);
    float d[8];
#pragma unroll
    for (int j = 0; j < 8; ++j) d[j] = reduce16(p[j]);

    float hv = tanh_fast(select8(d, jsel) + a);
    if (qq < 8) {
      hbuf[(s + 1) & 1][LIDX(o_sel)] = hv;
      hsb[s * H_ + o_sel] = hv;
    }
    a = a_next;
    __syncthreads();
  }
}

// ---------------------------------------------------------------------------
// K3: fused scores + online softmax + context numerator over a seq-quarter.
// Lane qq<8 carries the (m,l,N) state for output og+32*qq (qq>=8 redundant).
// ---------------------------------------------------------------------------
__global__ __launch_bounds__(512, 2) void attn_part_k(const float* __restrict__ hs,
                                                      const float* __restrict__ Wattn,
                                                      const float* __restrict__ battn,
                                                      float* __restrict__ part) {
  const int t = threadIdx.x;
  const int b = blockIdx.x >> 2, quarter = blockIdx.x & 3;
  const int qq = t & 15, og = t >> 4;
  const int jsel = qq & 7;
  const int o_sel = og + 32 * jsel;

  float4 w[8][4];
  LOAD_W8(w, Wattn, og + 32 * j, qq);

  __shared__ __align__(16) float hrow[2][HBUF_W];
  const float* base = hs + ((size_t)b * S_ + (size_t)quarter * (S_ / 4)) * H_;
  if (t < 64)
    reinterpret_cast<float4*>(&hrow[0][(t >> 2) * CH_W])[t & 3] =
        reinterpret_cast<const float4*>(base)[t];
  const float ba = battn[o_sel];
  float m = -3.0e38f, l = 0.f, N = 0.f;
  __syncthreads();

  for (int i = 0; i < S_ / 4; ++i) {
    float4 nv;
    const bool pf = (t < 64) && (i + 1 < S_ / 4);
    if (pf) nv = reinterpret_cast<const float4*>(base + (size_t)(i + 1) * H_)[t];

    const float* hb = hrow[i & 1];
    const float4* hq4 = reinterpret_cast<const float4*>(&hb[qq * CH_W]);
    float p[8];
    DOT8x16(p, w, hq4);
    float d[8];
#pragma unroll
    for (int j = 0; j < 8; ++j) d[j] = reduce16(p[j]);

    float sc = select8(d, jsel) + ba;
    float hval = hb[LIDX(o_sel)];
    float mn = fmaxf(m, sc);
    float scale = __expf(m - mn);
    float e = __expf(sc - mn);
    l = l * scale + e;
    N = N * scale + e * hval;
    m = mn;

    if (pf)
      reinterpret_cast<float4*>(&hrow[(i + 1) & 1][(t >> 2) * CH_W])[t & 3] = nv;
    __syncthreads();
  }
  if (qq < 8) {
    float* pb = part + (size_t)blockIdx.x * 3 * H_;
    pb[o_sel] = m;
    pb[H_ + o_sel] = l;
    pb[2 * H_ + o_sel] = N;
  }
}

// ---------------------------------------------------------------------------
// K3b: merge 4 sequence-quarter partials -> context[b,h] = N/l
// ---------------------------------------------------------------------------
__global__ __launch_bounds__(256) void attn_merge(const float* __restrict__ part,
                                                  float* __restrict__ ctx) {
  const int b = blockIdx.x, t = threadIdx.x;
  float m = -3.0e38f, l = 0.f, N = 0.f;
#pragma unroll
  for (int j = 0; j < 4; ++j) {
    const float* pb = part + (size_t)(b * 4 + j) * 3 * H_;
    float m2 = pb[t], l2 = pb[H_ + t], N2 = pb[2 * H_ + t];
    float mn = fmaxf(m, m2);
    float A1 = __expf(m - mn), A2 = __expf(m2 - mn);
    l = l * A1 + l2 * A2;
    N = N * A1 + N2 * A2;
    m = mn;
  }
  ctx[b * H_ + t] = N / l;
}

// ---------------------------------------------------------------------------
// K4: out = (hs + context) @ Wfc^T + bfc, in place over d_out. 16 rows/block
// staged (+ctx) into chunk-strided LDS; same 8x16 decomposition per row.
// ---------------------------------------------------------------------------
__global__ __launch_bounds__(512, 2) void out_gemm(float* __restrict__ data,
                                                   const float* __restrict__ Wfc,
                                                   const float* __restrict__ bfc,
                                                   const float* __restrict__ ctx) {
  const int t = threadIdx.x;
  const int tile = blockIdx.x;  // 16 rows; 64 tiles per batch
  const int b = tile >> 6;
  const size_t r0 = (size_t)tile * 16;
  const int qq = t & 15, vg = t >> 4;
  const int jsel = qq & 7;
  const int v_sel = vg + 32 * jsel;

  float4 w[8][4];
  LOAD_W8(w, Wfc, vg + 32 * j, qq);

  __shared__ __align__(16) float comb[16][HBUF_W];
  {
    const float4* src = reinterpret_cast<const float4*>(data + r0 * H_);
    const float4* cx4 = reinterpret_cast<const float4*>(ctx + b * H_);
#pragma unroll
    for (int u = 0; u < 2; ++u) {
      int f4 = t + u * 512;  // [0,1024): row = f4/64, float4-col = f4%64
      int row = f4 >> 6, c4 = f4 & 63;
      float4 v = src[f4];
      float4 c = cx4[c4];
      v.x += c.x; v.y += c.y; v.z += c.z; v.w += c.w;
      reinterpret_cast<float4*>(&comb[row][(c4 >> 2) * CH_W])[c4 & 3] = v;
    }
  }
  const float bv = bfc[v_sel];
  __syncthreads();

#pragma unroll 1
  for (int r = 0; r < 16; ++r) {
    const float4* hq4 = reinterpret_cast<const float4*>(&comb[r][qq * CH_W]);
    float p[8];
    DOT8x16(p, w, hq4);
    float d[8];
#pragma unroll
    for (int j = 0; j < 8; ++j) d[j] = reduce16(p[j]);
    float out = select8(d, jsel) + bv;
    if (qq < 8) data[(r0 + r) * H_ + v_sel] = out;
  }
}

// ---------------------------------------------------------------------------
extern "C" void kernel_launch(void* const* d_in, const int* in_sizes, int n_in,
                              void* d_out, int out_size, void* d_ws, size_t ws_size,
                              hipStream_t stream) {
  const int* x = (const int*)d_in[0];
  const float* embed = (const float*)d_in[1];
  const float* Wxh = (const float*)d_in[2];
  const float* bxh = (const float*)d_in[3];
  const float* Whh = (const float*)d_in[4];
  const float* bhh = (const float*)d_in[5];
  const float* Wattn = (const float*)d_in[6];
  const float* battn = (const float*)d_in[7];
  const float* Wfc = (const float*)d_in[8];
  const float* bfc = (const float*)d_in[9];
  float* out = (float*)d_out;

  float* A = (float*)d_ws;              // V*H
  float* part = A + V_ * H_;            // B*4*3*H
  float* ctx = part + B_ * 4 * 3 * H_;  // B*H

  prep_A<<<V_, 512, 0, stream>>>(embed, Wxh, bxh, bhh, A);
  rnn_fwd<<<B_, 512, 0, stream>>>(x, A, Whh, out);
  attn_part_k<<<B_ * 4, 512, 0, stream>>>(out, Wattn, battn, part);
  attn_merge<<<B_, 256, 0, stream>>>(part, ctx);
  out_gemm<<<B_ * S_ / 16, 512, 0, stream>>>(out, Wfc, bfc, ctx);
}

// Round 4
// 1524.701 us; speedup vs baseline: 1.2064x; 1.2064x over previous
//
#include <hip/hip_runtime.h>

#define B_ 128
#define S_ 1024
#define H_ 256
#define V_ 256

// LDS layout: 8 chunks of 32 floats at 36-word stride. A wave's 8 distinct
// ds_read_b128 addresses start at banks {0,4,...,28} (qq*36 mod 32 = 4*qq):
// one address per 4-bank quad, broadcast to 8 lanes -> conflict-free.
#define CH 36
#define LIDX(e) ((((e) >> 5) * CH) + ((e) & 31))
#define HBUF_W (8 * CH)  // 288 words per h-vector

#define DPP_ADD(v, ctrl)                                                      \
  v += __int_as_float(                                                        \
      __builtin_amdgcn_update_dpp(0, __float_as_int(v), ctrl, 0xF, 0xF, true))

// sum across each aligned 8-lane group, all on the VALU pipe (DPP)
__device__ __forceinline__ float reduce8(float v) {
  DPP_ADD(v, 0xB1);   // quad_perm [1,0,3,2]  (xor 1)
  DPP_ADD(v, 0x4E);   // quad_perm [2,3,0,1]  (xor 2)
  DPP_ADD(v, 0x141);  // row_half_mirror: i <-> 7-i within 8 (other quad)
  return v;
}

__device__ __forceinline__ float select4(const float d[4], int j) {
  float s01 = (j & 1) ? d[1] : d[0];
  float s23 = (j & 1) ? d[3] : d[2];
  return (j & 2) ? s23 : s01;
}

__device__ __forceinline__ float tanh_fast(float x) {
  x = fminf(fmaxf(x, -15.f), 15.f);
  float e = __expf(2.f * x);
  return (e - 1.f) * __builtin_amdgcn_rcpf(e + 1.f);
}

// d[j] = w[j][:] . h (32 floats), 16 independent accumulator chains
__device__ __forceinline__ void dot4x32(const float4 w[4][8], const float4 h[8],
                                        float d[4]) {
#pragma unroll
  for (int j = 0; j < 4; ++j) {
    float a0 = 0.f, a1 = 0.f, a2 = 0.f, a3 = 0.f;
#pragma unroll
    for (int u = 0; u < 8; u += 2) {
      float4 w0 = w[j][u], w1 = w[j][u + 1];
      float4 x0 = h[u], x1 = h[u + 1];
      a0 += w0.x * x0.x; a1 += w0.y * x0.y;
      a2 += w0.z * x0.z; a3 += w0.w * x0.w;
      a0 += w1.x * x1.x; a1 += w1.y * x1.y;
      a2 += w1.z * x1.z; a3 += w1.w * x1.w;
    }
    d[j] = (a0 + a1) + (a2 + a3);
  }
}

#define LOAD_W4(w, SRC, og, kb)                                               \
  _Pragma("unroll") for (int j = 0; j < 4; ++j) {                             \
    const float4* W =                                                         \
        reinterpret_cast<const float4*>((SRC) + (size_t)((og) + 64 * j) * H_ + (kb)); \
    _Pragma("unroll") for (int u = 0; u < 8; ++u) w[j][u] = W[u];             \
  }

// ---------------------------------------------------------------------------
// K1: A[v,h] = embed[v,:]·Wxh[h,:] + bxh[h] + bhh[h]
// ---------------------------------------------------------------------------
__global__ __launch_bounds__(512, 2) void prep_A(const float* __restrict__ embed,
                                                 const float* __restrict__ Wxh,
                                                 const float* __restrict__ bxh,
                                                 const float* __restrict__ bhh,
                                                 float* __restrict__ A) {
  const int v = blockIdx.x, t = threadIdx.x;
  const int qq = t & 7, og = t >> 3;
  const int jsel = qq & 3;
  const int o_sel = og + 64 * jsel;
  const int kb = qq * 32;

  __shared__ __align__(16) float erow[HBUF_W];
  if (t < 64)
    reinterpret_cast<float4*>(&erow[(t >> 3) * CH])[t & 7] =
        reinterpret_cast<const float4*>(embed + v * H_)[t];

  float4 w[4][8];
  LOAD_W4(w, Wxh, og, kb);
  __syncthreads();

  float4 h4[8];
  {
    const float4* p = reinterpret_cast<const float4*>(&erow[qq * CH]);
#pragma unroll
    for (int u = 0; u < 8; ++u) h4[u] = p[u];
  }
  float d[4];
  dot4x32(w, h4, d);
#pragma unroll
  for (int j = 0; j < 4; ++j) d[j] = reduce8(d[j]);
  if (qq < 4) A[v * H_ + o_sel] = select4(d, jsel) + bxh[o_sel] + bhh[o_sel];
}

// ---------------------------------------------------------------------------
// K2: Elman recurrence. One block/batch; thread (og,qq) owns outputs
// {og+64j, j<4} with k-chunk [32qq,32qq+32). 8 conflict-free b128/thread/step,
// DPP butterfly reduce, one barrier/step.
// ---------------------------------------------------------------------------
__global__ __launch_bounds__(512, 2) void rnn_fwd(const int* __restrict__ x,
                                                  const float* __restrict__ A,
                                                  const float* __restrict__ Whh,
                                                  float* __restrict__ hs) {
  const int t = threadIdx.x, b = blockIdx.x;
  const int qq = t & 7, og = t >> 3;
  const int jsel = qq & 3;
  const int o_sel = og + 64 * jsel;
  const int kb = qq * 32;

  float4 w[4][8];
  LOAD_W4(w, Whh, og, kb);

  __shared__ __align__(16) float hbuf[2][HBUF_W];
  if (t < H_) hbuf[0][LIDX(t)] = 0.f;
  const int* xb = x + b * S_;
  float* hsb = hs + (size_t)b * S_ * H_;
  float a = A[xb[0] * H_ + o_sel];
  __syncthreads();

  for (int s = 0; s < S_; ++s) {
    float4 h4[8];
    {
      const float4* p = reinterpret_cast<const float4*>(&hbuf[s & 1][qq * CH]);
#pragma unroll
      for (int u = 0; u < 8; ++u) h4[u] = p[u];
    }
    float a_next = (s + 1 < S_) ? A[xb[s + 1] * H_ + o_sel] : 0.f;

    float d[4];
    dot4x32(w, h4, d);
#pragma unroll
    for (int j = 0; j < 4; ++j) d[j] = reduce8(d[j]);

    float hv = tanh_fast(select4(d, jsel) + a);
    if (qq < 4) {
      hbuf[(s + 1) & 1][LIDX(o_sel)] = hv;  // writes buffer not read this step
      hsb[s * H_ + o_sel] = hv;
    }
    a = a_next;
    __syncthreads();
  }
}

// ---------------------------------------------------------------------------
// K3: fused scores + online softmax + context numerator over a seq-quarter.
// All 8 qq lanes of a group carry identical (m,l,N) after reduce8; qq<4 write.
// ---------------------------------------------------------------------------
__global__ __launch_bounds__(512, 2) void attn_part_k(const float* __restrict__ hs,
                                                      const float* __restrict__ Wattn,
                                                      const float* __restrict__ battn,
                                                      float* __restrict__ part) {
  const int t = threadIdx.x;
  const int b = blockIdx.x >> 2, quarter = blockIdx.x & 3;
  const int qq = t & 7, og = t >> 3;
  const int jsel = qq & 3;
  const int o_sel = og + 64 * jsel;
  const int kb = qq * 32;

  float4 w[4][8];
  LOAD_W4(w, Wattn, og, kb);

  __shared__ __align__(16) float hrow[2][HBUF_W];
  const float* base = hs + ((size_t)b * S_ + (size_t)quarter * (S_ / 4)) * H_;
  if (t < 64)
    reinterpret_cast<float4*>(&hrow[0][(t >> 3) * CH])[t & 7] =
        reinterpret_cast<const float4*>(base)[t];
  const float ba = battn[o_sel];
  float m = -3.0e38f, l = 0.f, N = 0.f;
  __syncthreads();

  for (int i = 0; i < S_ / 4; ++i) {
    float4 nv;
    const bool pf = (t < 64) && (i + 1 < S_ / 4);
    if (pf) nv = reinterpret_cast<const float4*>(base + (size_t)(i + 1) * H_)[t];

    const float* hb = hrow[i & 1];
    float4 h4[8];
    {
      const float4* p = reinterpret_cast<const float4*>(&hb[qq * CH]);
#pragma unroll
      for (int u = 0; u < 8; ++u) h4[u] = p[u];
    }
    float d[4];
    dot4x32(w, h4, d);
#pragma unroll
    for (int j = 0; j < 4; ++j) d[j] = reduce8(d[j]);

    float sc = select4(d, jsel) + ba;
    float hval = hb[LIDX(o_sel)];
    float mn = fmaxf(m, sc);
    float scale = __expf(m - mn);
    float e = __expf(sc - mn);
    l = l * scale + e;
    N = N * scale + e * hval;
    m = mn;

    if (pf)
      reinterpret_cast<float4*>(&hrow[(i + 1) & 1][(t >> 3) * CH])[t & 7] = nv;
    __syncthreads();
  }
  if (qq < 4) {
    float* pb = part + (size_t)blockIdx.x * 3 * H_;
    pb[o_sel] = m;
    pb[H_ + o_sel] = l;
    pb[2 * H_ + o_sel] = N;
  }
}

// ---------------------------------------------------------------------------
// K3b: merge 4 sequence-quarter partials -> context[b,h] = N/l
// ---------------------------------------------------------------------------
__global__ __launch_bounds__(256) void attn_merge(const float* __restrict__ part,
                                                  float* __restrict__ ctx) {
  const int b = blockIdx.x, t = threadIdx.x;
  float m = -3.0e38f, l = 0.f, N = 0.f;
#pragma unroll
  for (int j = 0; j < 4; ++j) {
    const float* pb = part + (size_t)(b * 4 + j) * 3 * H_;
    float m2 = pb[t], l2 = pb[H_ + t], N2 = pb[2 * H_ + t];
    float mn = fmaxf(m, m2);
    float A1 = __expf(m - mn), A2 = __expf(m2 - mn);
    l = l * A1 + l2 * A2;
    N = N * A1 + N2 * A2;
    m = mn;
  }
  ctx[b * H_ + t] = N / l;
}

// ---------------------------------------------------------------------------
// K4: out = (hs + context) @ Wfc^T + bfc, in place over d_out. 16 rows/block
// staged (+ctx) into conflict-free LDS; same 4x8 decomposition per row.
// ---------------------------------------------------------------------------
__global__ __launch_bounds__(512, 2) void out_gemm(float* __restrict__ data,
                                                   const float* __restrict__ Wfc,
                                                   const float* __restrict__ bfc,
                                                   const float* __restrict__ ctx) {
  const int t = threadIdx.x;
  const int tile = blockIdx.x;  // 16 rows; 64 tiles per batch
  const int b = tile >> 6;
  const size_t r0 = (size_t)tile * 16;
  const int qq = t & 7, vg = t >> 3;
  const int jsel = qq & 3;
  const int v_sel = vg + 64 * jsel;
  const int kb = qq * 32;

  float4 w[4][8];
  LOAD_W4(w, Wfc, vg, kb);

  __shared__ __align__(16) float comb[16][HBUF_W];
  {
    const float4* src = reinterpret_cast<const float4*>(data + r0 * H_);
    const float4* cx4 = reinterpret_cast<const float4*>(ctx + b * H_);
#pragma unroll
    for (int u = 0; u < 2; ++u) {
      int f4 = t + u * 512;  // [0,1024): row = f4/64, float4-col = f4%64
      int row = f4 >> 6, c4 = f4 & 63;
      float4 v = src[f4];
      float4 c = cx4[c4];
      v.x += c.x; v.y += c.y; v.z += c.z; v.w += c.w;
      reinterpret_cast<float4*>(&comb[row][(c4 >> 3) * CH])[c4 & 7] = v;
    }
  }
  const float bv = bfc[v_sel];
  __syncthreads();

#pragma unroll 1
  for (int r = 0; r < 16; ++r) {
    float4 h4[8];
    {
      const float4* p = reinterpret_cast<const float4*>(&comb[r][qq * CH]);
#pragma unroll
      for (int u = 0; u < 8; ++u) h4[u] = p[u];
    }
    float d[4];
    dot4x32(w, h4, d);
#pragma unroll
    for (int j = 0; j < 4; ++j) d[j] = reduce8(d[j]);
    if (qq < 4) data[(r0 + r) * H_ + v_sel] = select4(d, jsel) + bv;
  }
}

// ---------------------------------------------------------------------------
extern "C" void kernel_launch(void* const* d_in, const int* in_sizes, int n_in,
                              void* d_out, int out_size, void* d_ws, size_t ws_size,
                              hipStream_t stream) {
  const int* x = (const int*)d_in[0];
  const float* embed = (const float*)d_in[1];
  const float* Wxh = (const float*)d_in[2];
  const float* bxh = (const float*)d_in[3];
  const float* Whh = (const float*)d_in[4];
  const float* bhh = (const float*)d_in[5];
  const float* Wattn = (const float*)d_in[6];
  const float* battn = (const float*)d_in[7];
  const float* Wfc = (const float*)d_in[8];
  const float* bfc = (const float*)d_in[9];
  float* out = (float*)d_out;

  float* A = (float*)d_ws;              // V*H
  float* part = A + V_ * H_;            // B*4*3*H
  float* ctx = part + B_ * 4 * 3 * H_;  // B*H

  prep_A<<<V_, 512, 0, stream>>>(embed, Wxh, bxh, bhh, A);
  rnn_fwd<<<B_, 512, 0, stream>>>(x, A, Whh, out);
  attn_part_k<<<B_ * 4, 512, 0, stream>>>(out, Wattn, battn, part);
  attn_merge<<<B_, 256, 0, stream>>>(part, ctx);
  out_gemm<<<B_ * S_ / 16, 512, 0, stream>>>(out, Wfc, bfc, ctx);
}

// Round 5
// 901.450 us; speedup vs baseline: 2.0406x; 1.6914x over previous
//
#include <hip/hip_runtime.h>

#define B_ 128
#define S_ 1024
#define H_ 256
#define V_ 256

typedef short bf8 __attribute__((ext_vector_type(8)));
typedef float f32x4 __attribute__((ext_vector_type(4)));

// XOR-swizzle within a 512B LDS row (16B granularity) — spreads the 16-row
// column-slice reads of MFMA A-fragments across 8 bank quads (G4 pattern).
#define SWZB(row, byt) ((byt) ^ (((row)&7) << 4))

__device__ __forceinline__ unsigned short f32_bf16(float f) {
  unsigned int u = __float_as_uint(f);
  unsigned int r = (u + 0x7FFFu + ((u >> 16) & 1u)) >> 16;  // RNE
  return (unsigned short)r;
}
__device__ __forceinline__ float bf16_f32(unsigned short h) {
  return __uint_as_float((unsigned int)h << 16);
}

// ======================= fp32 VALU helpers (RNN path) =======================
#define CH 36
#define LIDX(e) ((((e) >> 5) * CH) + ((e) & 31))
#define HBUF_W (8 * CH)

#define DPP_ADD(v, ctrl)                                                      \
  v += __int_as_float(                                                        \
      __builtin_amdgcn_update_dpp(0, __float_as_int(v), ctrl, 0xF, 0xF, true))

__device__ __forceinline__ float reduce8(float v) {
  DPP_ADD(v, 0xB1);
  DPP_ADD(v, 0x4E);
  DPP_ADD(v, 0x141);
  return v;
}

__device__ __forceinline__ float select4(const float d[4], int j) {
  float s01 = (j & 1) ? d[1] : d[0];
  float s23 = (j & 1) ? d[3] : d[2];
  return (j & 2) ? s23 : s01;
}

__device__ __forceinline__ float tanh_fast(float x) {
  x = fminf(fmaxf(x, -15.f), 15.f);
  float e = __expf(2.f * x);
  return (e - 1.f) * __builtin_amdgcn_rcpf(e + 1.f);
}

__device__ __forceinline__ void dot4x32(const float4 w[4][8], const float4 h[8],
                                        float d[4]) {
#pragma unroll
  for (int j = 0; j < 4; ++j) {
    float a0 = 0.f, a1 = 0.f, a2 = 0.f, a3 = 0.f;
#pragma unroll
    for (int u = 0; u < 8; u += 2) {
      float4 w0 = w[j][u], w1 = w[j][u + 1];
      float4 x0 = h[u], x1 = h[u + 1];
      a0 += w0.x * x0.x; a1 += w0.y * x0.y;
      a2 += w0.z * x0.z; a3 += w0.w * x0.w;
      a0 += w1.x * x1.x; a1 += w1.y * x1.y;
      a2 += w1.z * x1.z; a3 += w1.w * x1.w;
    }
    d[j] = (a0 + a1) + (a2 + a3);
  }
}

#define LOAD_W4(w, SRC, og, kb)                                               \
  _Pragma("unroll") for (int j = 0; j < 4; ++j) {                             \
    const float4* W =                                                         \
        reinterpret_cast<const float4*>((SRC) + (size_t)((og) + 64 * j) * H_ + (kb)); \
    _Pragma("unroll") for (int u = 0; u < 8; ++u) w[j][u] = W[u];             \
  }

// ---------------------------------------------------------------------------
// K1: A[v,h] = embed[v,:]·Wxh[h,:] + bxh[h] + bhh[h]
// ---------------------------------------------------------------------------
__global__ __launch_bounds__(512, 2) void prep_A(const float* __restrict__ embed,
                                                 const float* __restrict__ Wxh,
                                                 const float* __restrict__ bxh,
                                                 const float* __restrict__ bhh,
                                                 float* __restrict__ A) {
  const int v = blockIdx.x, t = threadIdx.x;
  const int qq = t & 7, og = t >> 3;
  const int jsel = qq & 3;
  const int o_sel = og + 64 * jsel;
  const int kb = qq * 32;

  __shared__ __align__(16) float erow[HBUF_W];
  if (t < 64)
    reinterpret_cast<float4*>(&erow[(t >> 3) * CH])[t & 7] =
        reinterpret_cast<const float4*>(embed + v * H_)[t];

  float4 w[4][8];
  LOAD_W4(w, Wxh, og, kb);
  __syncthreads();

  float4 h4[8];
  {
    const float4* p = reinterpret_cast<const float4*>(&erow[qq * CH]);
#pragma unroll
    for (int u = 0; u < 8; ++u) h4[u] = p[u];
  }
  float d[4];
  dot4x32(w, h4, d);
#pragma unroll
  for (int j = 0; j < 4; ++j) d[j] = reduce8(d[j]);
  if (qq < 4) A[v * H_ + o_sel] = select4(d, jsel) + bxh[o_sel] + bhh[o_sel];
}

// ---------------------------------------------------------------------------
// K2: Elman recurrence (fp32 state). hs snapshot stored as bf16 in the first
// 512B of each 1KB output-row slot of d_out (out_mfma later overwrites).
// ---------------------------------------------------------------------------
__global__ __launch_bounds__(512, 2) void rnn_fwd(const int* __restrict__ x,
                                                  const float* __restrict__ A,
                                                  const float* __restrict__ Whh,
                                                  unsigned short* __restrict__ hsu) {
  const int t = threadIdx.x, b = blockIdx.x;
  const int qq = t & 7, og = t >> 3;
  const int jsel = qq & 3;
  const int o_sel = og + 64 * jsel;
  const int kb = qq * 32;

  float4 w[4][8];
  LOAD_W4(w, Whh, og, kb);

  __shared__ __align__(16) float hbuf[2][HBUF_W];
  if (t < H_) hbuf[0][LIDX(t)] = 0.f;
  const int* xb = x + b * S_;
  unsigned short* hrow = hsu + (size_t)b * S_ * 512;
  float a = A[xb[0] * H_ + o_sel];
  __syncthreads();

  for (int s = 0; s < S_; ++s) {
    float4 h4[8];
    {
      const float4* p = reinterpret_cast<const float4*>(&hbuf[s & 1][qq * CH]);
#pragma unroll
      for (int u = 0; u < 8; ++u) h4[u] = p[u];
    }
    float a_next = (s + 1 < S_) ? A[xb[s + 1] * H_ + o_sel] : 0.f;

    float d[4];
    dot4x32(w, h4, d);
#pragma unroll
    for (int j = 0; j < 4; ++j) d[j] = reduce8(d[j]);

    float hv = tanh_fast(select4(d, jsel) + a);
    if (qq < 4) {
      hbuf[(s + 1) & 1][LIDX(o_sel)] = hv;
      hrow[(size_t)s * 512 + o_sel] = f32_bf16(hv);
    }
    a = a_next;
    __syncthreads();
  }
}

// ---------------------------------------------------------------------------
// K3: MFMA flash-attn scores + online softmax + context numerator.
// Block = (batch, seq-quarter); 8 waves; wave owns a 32-col N-slice with
// Wattn B-frags in regs; hs chunk (128x256 bf16) in XOR-swizzled LDS.
// ---------------------------------------------------------------------------
__global__ __launch_bounds__(512, 1) void attn_mfma(const unsigned short* __restrict__ hsu,
                                                    const float* __restrict__ Wattn,
                                                    const float* __restrict__ battn,
                                                    float* __restrict__ part) {
  const int tid = threadIdx.x;
  const int wave = tid >> 6, lane = tid & 63;
  const int l15 = lane & 15, l4 = lane >> 4;
  const int b = blockIdx.x >> 2, quarter = blockIdx.x & 3;

  __shared__ __align__(16) char tile[128 * 512];

  bf8 bfr[2][8];
  float bias[2];
#pragma unroll
  for (int nt = 0; nt < 2; ++nt) {
    const int c = wave * 32 + nt * 16 + l15;
    bias[nt] = battn[c];
#pragma unroll
    for (int kt = 0; kt < 8; ++kt) {
      const float* wp = Wattn + (size_t)c * H_ + kt * 32 + l4 * 8;
      bf8 v;
#pragma unroll
      for (int j = 0; j < 8; ++j) v[j] = (short)f32_bf16(wp[j]);
      bfr[nt][kt] = v;
    }
  }

  float m[2] = {-3e38f, -3e38f}, lsum[2] = {0.f, 0.f}, nsum[2] = {0.f, 0.f};

  for (int chunk = 0; chunk < 2; ++chunk) {
    const size_t row0 = (size_t)b * S_ + quarter * 256 + chunk * 128;
    {  // stage 128 rows x 512B bf16 into swizzled LDS
      const int r = tid >> 2, qt = tid & 3;
      const uint4* gp =
          reinterpret_cast<const uint4*>(hsu + (row0 + r) * 512 + qt * 64);
      char* dst = tile + r * 512;
#pragma unroll
      for (int i = 0; i < 8; ++i) {
        uint4 v = gp[i];
        *reinterpret_cast<uint4*>(dst + SWZB(r, qt * 128 + i * 16)) = v;
      }
    }
    __syncthreads();

    f32x4 acc[8][2];
#pragma unroll
    for (int mt = 0; mt < 8; ++mt) {
      acc[mt][0] = (f32x4){0.f, 0.f, 0.f, 0.f};
      acc[mt][1] = (f32x4){0.f, 0.f, 0.f, 0.f};
    }
#pragma unroll
    for (int kt = 0; kt < 8; ++kt) {
#pragma unroll
      for (int mt = 0; mt < 8; ++mt) {
        const int row = mt * 16 + l15;
        bf8 a = *reinterpret_cast<const bf8*>(
            tile + row * 512 + SWZB(row, kt * 64 + l4 * 16));
        acc[mt][0] = __builtin_amdgcn_mfma_f32_16x16x32_bf16(a, bfr[0][kt],
                                                             acc[mt][0], 0, 0, 0);
        acc[mt][1] = __builtin_amdgcn_mfma_f32_16x16x32_bf16(a, bfr[1][kt],
                                                             acc[mt][1], 0, 0, 0);
      }
    }

#pragma unroll
    for (int nt = 0; nt < 2; ++nt) {
      const int c = wave * 32 + nt * 16 + l15;
      float mx = -3e38f;
#pragma unroll
      for (int mt = 0; mt < 8; ++mt)
#pragma unroll
        for (int r = 0; r < 4; ++r) mx = fmaxf(mx, acc[mt][nt][r]);
      mx = fmaxf(mx, __shfl_xor(mx, 16));
      mx = fmaxf(mx, __shfl_xor(mx, 32));
      mx += bias[nt];
      const float newm = fmaxf(m[nt], mx);
      const float scale = __expf(m[nt] - newm);
      float es = 0.f, ew = 0.f;
#pragma unroll
      for (int mt = 0; mt < 8; ++mt) {
#pragma unroll
        for (int r = 0; r < 4; ++r) {
          const int s = mt * 16 + l4 * 4 + r;
          float e = __expf(acc[mt][nt][r] + bias[nt] - newm);
          unsigned short hb =
              *reinterpret_cast<const unsigned short*>(tile + s * 512 + SWZB(s, 2 * c));
          es += e;
          ew += e * bf16_f32(hb);
        }
      }
      es += __shfl_xor(es, 16);
      es += __shfl_xor(es, 32);
      ew += __shfl_xor(ew, 16);
      ew += __shfl_xor(ew, 32);
      lsum[nt] = lsum[nt] * scale + es;
      nsum[nt] = nsum[nt] * scale + ew;
      m[nt] = newm;
    }
    __syncthreads();  // LDS reads done before next chunk restages
  }

  if (lane < 16) {
    float* pb = part + (size_t)blockIdx.x * 768;
#pragma unroll
    for (int nt = 0; nt < 2; ++nt) {
      const int c = wave * 32 + nt * 16 + lane;
      pb[c] = m[nt];
      pb[256 + c] = lsum[nt];
      pb[512 + c] = nsum[nt];
    }
  }
}

// ---------------------------------------------------------------------------
// K3b: merge 4 quarter-partials -> ctx, then cvec[b,v] = ctx·Wfc[v,:] + bfc[v]
// ---------------------------------------------------------------------------
__global__ __launch_bounds__(256) void merge_cvec(const float* __restrict__ part,
                                                  const float* __restrict__ Wfc,
                                                  const float* __restrict__ bfc,
                                                  float* __restrict__ cvec) {
  const int b = blockIdx.x, t = threadIdx.x;
  __shared__ __align__(16) float ctx[H_];
  float m = -3e38f, l = 0.f, N = 0.f;
#pragma unroll
  for (int j = 0; j < 4; ++j) {
    const float* pb = part + (size_t)(b * 4 + j) * 768;
    float m2 = pb[t], l2 = pb[256 + t], N2 = pb[512 + t];
    float mn = fmaxf(m, m2);
    float A1 = __expf(m - mn), A2 = __expf(m2 - mn);
    l = l * A1 + l2 * A2;
    N = N * A1 + N2 * A2;
    m = mn;
  }
  ctx[t] = N / l;
  __syncthreads();

  const float4* wr = reinterpret_cast<const float4*>(Wfc + (size_t)t * H_);
  const float4* cx = reinterpret_cast<const float4*>(ctx);
  float a0 = 0.f, a1 = 0.f, a2 = 0.f, a3 = 0.f;
#pragma unroll
  for (int q = 0; q < H_ / 4; ++q) {
    float4 w = wr[q], c = cx[q];
    a0 += w.x * c.x;
    a1 += w.y * c.y;
    a2 += w.z * c.z;
    a3 += w.w * c.w;
  }
  cvec[b * H_ + t] = (a0 + a1) + (a2 + a3) + bfc[t];
}

// ---------------------------------------------------------------------------
// K4: out = hs @ Wfc^T + cvec[b,:], bf16 MFMA. Block = 128 rows; stages its
// own rows' bf16 hs to LDS, then overwrites those rows with fp32 out.
// ---------------------------------------------------------------------------
__global__ __launch_bounds__(512, 1) void out_mfma(float* __restrict__ outp,
                                                   const unsigned short* __restrict__ hsu,
                                                   const float* __restrict__ Wfc,
                                                   const float* __restrict__ cvec) {
  const int tid = threadIdx.x;
  const int wave = tid >> 6, lane = tid & 63;
  const int l15 = lane & 15, l4 = lane >> 4;
  const size_t row0 = (size_t)blockIdx.x * 128;
  const int b = blockIdx.x >> 3;

  __shared__ __align__(16) char tile[128 * 512];

  bf8 bfr[2][8];
  float cv[2];
#pragma unroll
  for (int nt = 0; nt < 2; ++nt) {
    const int c = wave * 32 + nt * 16 + l15;
    cv[nt] = cvec[b * H_ + c];
#pragma unroll
    for (int kt = 0; kt < 8; ++kt) {
      const float* wp = Wfc + (size_t)c * H_ + kt * 32 + l4 * 8;
      bf8 v;
#pragma unroll
      for (int j = 0; j < 8; ++j) v[j] = (short)f32_bf16(wp[j]);
      bfr[nt][kt] = v;
    }
  }

  {  // stage
    const int r = tid >> 2, qt = tid & 3;
    const uint4* gp =
        reinterpret_cast<const uint4*>(hsu + (row0 + r) * 512 + qt * 64);
    char* dst = tile + r * 512;
#pragma unroll
    for (int i = 0; i < 8; ++i) {
      uint4 v = gp[i];
      *reinterpret_cast<uint4*>(dst + SWZB(r, qt * 128 + i * 16)) = v;
    }
  }
  __syncthreads();

  f32x4 acc[8][2];
#pragma unroll
  for (int mt = 0; mt < 8; ++mt) {
    acc[mt][0] = (f32x4){0.f, 0.f, 0.f, 0.f};
    acc[mt][1] = (f32x4){0.f, 0.f, 0.f, 0.f};
  }
#pragma unroll
  for (int kt = 0; kt < 8; ++kt) {
#pragma unroll
    for (int mt = 0; mt < 8; ++mt) {
      const int row = mt * 16 + l15;
      bf8 a = *reinterpret_cast<const bf8*>(
          tile + row * 512 + SWZB(row, kt * 64 + l4 * 16));
      acc[mt][0] = __builtin_amdgcn_mfma_f32_16x16x32_bf16(a, bfr[0][kt],
                                                           acc[mt][0], 0, 0, 0);
      acc[mt][1] = __builtin_amdgcn_mfma_f32_16x16x32_bf16(a, bfr[1][kt],
                                                           acc[mt][1], 0, 0, 0);
    }
  }

#pragma unroll
  for (int mt = 0; mt < 8; ++mt) {
#pragma unroll
    for (int nt = 0; nt < 2; ++nt) {
      const int c = wave * 32 + nt * 16 + l15;
#pragma unroll
      for (int r = 0; r < 4; ++r) {
        const size_t row = row0 + mt * 16 + l4 * 4 + r;
        outp[row * H_ + c] = acc[mt][nt][r] + cv[nt];
      }
    }
  }
}

// ---------------------------------------------------------------------------
extern "C" void kernel_launch(void* const* d_in, const int* in_sizes, int n_in,
                              void* d_out, int out_size, void* d_ws, size_t ws_size,
                              hipStream_t stream) {
  const int* x = (const int*)d_in[0];
  const float* embed = (const float*)d_in[1];
  const float* Wxh = (const float*)d_in[2];
  const float* bxh = (const float*)d_in[3];
  const float* Whh = (const float*)d_in[4];
  const float* bhh = (const float*)d_in[5];
  const float* Wattn = (const float*)d_in[6];
  const float* battn = (const float*)d_in[7];
  const float* Wfc = (const float*)d_in[8];
  const float* bfc = (const float*)d_in[9];
  float* out = (float*)d_out;
  unsigned short* hsu = (unsigned short*)d_out;  // bf16 hs in row-slot halves

  float* A = (float*)d_ws;              // V*H
  float* part = A + V_ * H_;            // 512 * 768
  float* cvec = part + 512 * 768;       // B*H

  prep_A<<<V_, 512, 0, stream>>>(embed, Wxh, bxh, bhh, A);
  rnn_fwd<<<B_, 512, 0, stream>>>(x, A, Whh, hsu);
  attn_mfma<<<B_ * 4, 512, 0, stream>>>(hsu, Wattn, battn, part);
  merge_cvec<<<B_, 256, 0, stream>>>(part, Wfc, bfc, cvec);
  out_mfma<<<B_ * S_ / 128, 512, 0, stream>>>(out, hsu, Wfc, cvec);
}